// Round 5
// baseline (243.543 us; speedup 1.0000x reference)
//
#include <hip/hip_runtime.h>
#include <cstdint>
#include <cstddef>

// ---------------------------------------------------------------------------
// Differential attention forward, MI355X/gfx950.
// R4: isolate R3's failure. Attention = R2's proven math (swapped QK^T,
// in-reg softmax WITH defer-max, T12 pack) + ONLY the dbuf prefetch staging
// (issue-early / write-late, one barrier per kt). If this fails, the dbuf
// is the race; if it passes, no-max was the bug. GEMMs unchanged.
// ---------------------------------------------------------------------------

typedef short bf16x8 __attribute__((ext_vector_type(8)));
typedef float f32x4  __attribute__((ext_vector_type(4)));
typedef float f32x16 __attribute__((ext_vector_type(16)));
typedef unsigned short u16;
typedef u16 u16x4v __attribute__((ext_vector_type(4)));
typedef unsigned int u32;
typedef u32 u32x2 __attribute__((ext_vector_type(2)));
typedef u32 u32x4 __attribute__((ext_vector_type(4)));

#define LAMBDA_INIT 0.35550906759096926f
#define ONE_MINUS_LAMBDA_INIT 0.6444909324090307f
#define SCORE_SCALE 0.17677669529663687f   // 1/sqrt(32)

__device__ __forceinline__ u16 f2bf(float f) {
  uint32_t u = __float_as_uint(f);
  u += 0x7fffu + ((u >> 16) & 1u);          // round-to-nearest-even
  return (u16)(u >> 16);
}

__device__ __forceinline__ void gload_lds16(const void* g, void* lds) {
  __builtin_amdgcn_global_load_lds(
      (const __attribute__((address_space(1))) void*)g,
      (__attribute__((address_space(3))) void*)lds, 16, 0, 0);
}

__device__ __forceinline__ u32 cvtpk_bf16(float lo, float hi) {
  u32 r;
  asm("v_cvt_pk_bf16_f32 %0, %1, %2" : "=v"(r) : "v"(lo), "v"(hi));
  return r;
}

// exchange value with lane^32 partner (VALU-only, no LDS pipe)
__device__ __forceinline__ float xchg32f(float v, int hi) {
  u32x2 r = __builtin_amdgcn_permlane32_swap(__float_as_uint(v), __float_as_uint(v), false, false);
  return __uint_as_float(hi ? r.x : r.y);
}

__device__ __forceinline__ float rmax16(const f32x16& v) {
  float m = v[0];
#pragma unroll
  for (int i = 1; i < 16; ++i) m = fmaxf(m, v[i]);
  return m;
}

__device__ __forceinline__ float rsum16(const f32x16& v) {
  float a = 0.f;
#pragma unroll
  for (int i = 0; i < 16; ++i) a += v[i];
  return a;
}

// ---------------------------------------------------------------------------
// elementwise fp32 -> bf16 (x)
// ---------------------------------------------------------------------------
__global__ void conv_x_kernel(const float* __restrict__ in, u16* __restrict__ out, int n4) {
  int i = blockIdx.x * blockDim.x + threadIdx.x;
  if (i < n4) {
    float4 v = ((const float4*)in)[i];
    u16x4v o;
    o.x = f2bf(v.x); o.y = f2bf(v.y); o.z = f2bf(v.z); o.w = f2bf(v.w);
    ((u16x4v*)out)[i] = o;
  }
}

// ---------------------------------------------------------------------------
// W [K][N] fp32 -> WT [N][K] bf16 (64x64 LDS tile transpose)
// ---------------------------------------------------------------------------
__global__ void conv_transpose_kernel(const float* __restrict__ W, u16* __restrict__ WT,
                                      int K, int N) {
  __shared__ u16 L[64][72];
  const int n0 = blockIdx.x * 64, k0 = blockIdx.y * 64;
#pragma unroll
  for (int i = 0; i < 16; ++i) {
    int lin = i * 256 + threadIdx.x;
    int rr = lin >> 6, cc = lin & 63;
    L[rr][cc] = f2bf(W[(size_t)(k0 + rr) * N + n0 + cc]);
  }
  __syncthreads();
#pragma unroll
  for (int i = 0; i < 16; ++i) {
    int lin = i * 256 + threadIdx.x;
    int rr = lin >> 6, cc = lin & 63;
    WT[(size_t)(n0 + rr) * K + k0 + cc] = L[cc][rr];
  }
}

// ---------------------------------------------------------------------------
// bt-GEMM (m97 structure, unchanged)
// ---------------------------------------------------------------------------
template <typename OutT>
__global__ __launch_bounds__(256, 2) void gemm_bt(const u16* __restrict__ A,
                                                  const u16* __restrict__ Bt,
                                                  OutT* __restrict__ C,
                                                  int M, int N, int K) {
  __shared__ __align__(16) u16 As[2][128 * 32];
  __shared__ __align__(16) u16 Bs[2][128 * 32];
  const int wid = threadIdx.x >> 6, lane = threadIdx.x & 63;
  const int l15 = lane & 15, lhi = lane >> 4;
  const int wm = wid >> 1, wn = wid & 1;
  const int tm = blockIdx.x * 128, tn = blockIdx.y * 128;
  const int rr = lane >> 2, cb = (lane & 3) * 8;
  const int nkt = K >> 5;

  f32x4 acc[4][4];
#pragma unroll
  for (int m = 0; m < 4; ++m)
#pragma unroll
    for (int n = 0; n < 4; ++n) acc[m][n] = (f32x4){0.f, 0.f, 0.f, 0.f};

  auto stage = [&](int buf, int kt) {
#pragma unroll
    for (int i = 0; i < 2; ++i) {
      int lr = wid * 32 + i * 16;
      gload_lds16(A + (size_t)(tm + lr + rr) * K + kt * 32 + cb, &As[buf][lr * 32]);
      gload_lds16(Bt + (size_t)(tn + lr + rr) * K + kt * 32 + cb, &Bs[buf][lr * 32]);
    }
  };

  stage(0, 0);
  __syncthreads();
  int buf = 0;
  for (int kt = 0; kt < nkt; ++kt) {
    if (kt + 1 < nkt) stage(buf ^ 1, kt + 1);
    bf16x8 af[4], bfr[4];
#pragma unroll
    for (int m = 0; m < 4; ++m)
      af[m] = *(const bf16x8*)&As[buf][(wm * 64 + m * 16 + l15) * 32 + lhi * 8];
#pragma unroll
    for (int n = 0; n < 4; ++n)
      bfr[n] = *(const bf16x8*)&Bs[buf][(wn * 64 + n * 16 + l15) * 32 + lhi * 8];
#pragma unroll
    for (int m = 0; m < 4; ++m)
#pragma unroll
      for (int n = 0; n < 4; ++n)
        acc[m][n] = __builtin_amdgcn_mfma_f32_16x16x32_bf16(af[m], bfr[n], acc[m][n], 0, 0, 0);
    __syncthreads();
    buf ^= 1;
  }

#pragma unroll
  for (int m = 0; m < 4; ++m)
#pragma unroll
    for (int n = 0; n < 4; ++n)
#pragma unroll
      for (int r = 0; r < 4; ++r) {
        int row = tm + wm * 64 + m * 16 + lhi * 4 + r;
        int col = tn + wn * 64 + n * 16 + l15;
        float v = acc[m][n][r];
        if constexpr (sizeof(OutT) == 2)
          C[(size_t)row * N + col] = (OutT)f2bf(v);
        else
          C[(size_t)row * N + col] = v;
      }
}

// ---------------------------------------------------------------------------
// Fused differential flash attention + RMSNorm.
// R2 math (defer-max softmax) + dbuf prefetch staging (the ONLY R3 addition).
// Grid: 512 blocks XCD-swizzled; block = 4 waves x 32 q-rows; KVBLK=64.
// ---------------------------------------------------------------------------
#define KLD 32
#define VLD 72

__global__ __launch_bounds__(256, 2) void diff_attn_kernel(
    const u16* __restrict__ qkv,
    const float* __restrict__ lq1, const float* __restrict__ lk1,
    const float* __restrict__ lq2, const float* __restrict__ lk2,
    const float* __restrict__ rms_scale,
    u16* __restrict__ y) {
  __shared__ __align__(16) u16 K1s[2][64 * KLD];
  __shared__ __align__(16) u16 K2s[2][64 * KLD];
  __shared__ __align__(16) u16 VTs[2][64 * VLD];

  const int tid = threadIdx.x;
  const int wid = tid >> 6, lane = tid & 63;
  const int l31 = lane & 31, hi = lane >> 5;

  const int id = blockIdx.x;                 // 0..511
  const int swz = (id & 7) * 64 + (id >> 3); // XCD swizzle, 512 % 8 == 0
  const int qt = swz & 15;
  const int bh = swz >> 4;
  const int b = bh >> 4, head = bh & 15;
  const size_t row0 = (size_t)b * 2048;

  float d1 = 0.f, d2 = 0.f;
#pragma unroll
  for (int i = 0; i < 32; ++i) { d1 += lq1[i] * lk1[i]; d2 += lq2[i] * lk2[i]; }
  const float lam = expf(d1) - expf(d2) + LAMBDA_INIT;

  const int qrow = qt * 128 + wid * 32 + l31;
  const u16* qrp = qkv + (row0 + qrow) * 3072;
  bf16x8 q1f[2], q2f[2];
#pragma unroll
  for (int c = 0; c < 2; ++c) {
    q1f[c] = *(const bf16x8*)(qrp + head * 32 + c * 16 + hi * 8);
    q2f[c] = *(const bf16x8*)(qrp + 512 + head * 32 + c * 16 + hi * 8);
  }

  f32x16 o1[2], o2[2];
#pragma unroll
  for (int dt = 0; dt < 2; ++dt)
#pragma unroll
    for (int i = 0; i < 16; ++i) { o1[dt][i] = 0.f; o2[dt][i] = 0.f; }
  float m1 = -1e30f, m2 = -1e30f;
  float ls1 = 0.f, ls2 = 0.f;                // per-hi-half partial sums

  // staging helpers ---------------------------------------------------------
  auto issueK = [&](int buf, int kt) {
    const size_t krow0 = row0 + (size_t)kt * 64;
    const int srow = wid * 16 + (lane >> 2);
    const int gcol = 8 * ((lane & 3) ^ ((lane >> 3) & 3));  // pre-swizzled src
    const u16* g = qkv + (krow0 + srow) * 3072 + 1024 + head * 32 + gcol;
    gload_lds16(g, &K1s[buf][wid * 512]);
    gload_lds16(g + 512, &K2s[buf][wid * 512]);
  };
  auto loadV = [&](int kt, bf16x8* nv) {
    const size_t krow0 = row0 + (size_t)kt * 64;
#pragma unroll
    for (int h2 = 0; h2 < 2; ++h2) {
      int vid = h2 * 256 + tid;
      int vrow = vid >> 3, d0 = (vid & 7) * 8;
      nv[h2] = *(const bf16x8*)(qkv + (krow0 + vrow) * 3072 + 2048 + head * 64 + d0);
    }
  };
  auto writeV = [&](int buf, const bf16x8* nv) {
#pragma unroll
    for (int h2 = 0; h2 < 2; ++h2) {
      int vid = h2 * 256 + tid;
      int vrow = vid >> 3, d0 = (vid & 7) * 8;
      int wrow = vrow ^ (d0 & 56);           // swizzle: even bank coverage
#pragma unroll
      for (int e = 0; e < 8; ++e) VTs[buf][(d0 + e) * VLD + wrow] = (u16)nv[h2][e];
    }
  };

  // per-branch: swapped QK^T, defer-max softmax (R2 verbatim), T12 pack, PV --
  auto process = [&](const bf16x8* qf, const u16* Ks, const bf16x8 (*vf)[2][2],
                     float& m, float& ls, f32x16* o) {
    f32x16 s[2];
#pragma unroll
    for (int t = 0; t < 2; ++t) {
#pragma unroll
      for (int i = 0; i < 16; ++i) s[t][i] = 0.f;
      const int row = t * 32 + l31;
      const int sg = 8 * ((row >> 1) & 3);
#pragma unroll
      for (int c = 0; c < 2; ++c) {
        bf16x8 kf = *(const bf16x8*)&Ks[row * KLD + ((c * 16 + hi * 8) ^ sg)];
        s[t] = __builtin_amdgcn_mfma_f32_32x32x16_bf16(kf, qf[c], s[t], 0, 0, 0);
      }
    }
    // block max (in-lane over 32, then cross-hi)
    float pm = fmaxf(rmax16(s[0]), rmax16(s[1]));
    pm = fmaxf(pm, xchg32f(pm, hi));
    // defer-max (T13): only rescale when max grew by > 8 (raw-score domain)
    if (!__all(pm - m <= 8.0f)) {
      float mn = fmaxf(m, pm);
      float corr = __expf((m - mn) * SCORE_SCALE);
      m = mn;
      ls *= corr;
#pragma unroll
      for (int dt = 0; dt < 2; ++dt)
#pragma unroll
        for (int i = 0; i < 16; ++i) o[dt][i] *= corr;
    }
#pragma unroll
    for (int t = 0; t < 2; ++t)
#pragma unroll
      for (int i = 0; i < 16; ++i)
        s[t][i] = __expf((s[t][i] - m) * SCORE_SCALE);
    ls += rsum16(s[0]) + rsum16(s[1]);
    // pack P^T -> B-frags (8 cvt_pk + 4 permlane per 32-k tile) and PV
#pragma unroll
    for (int t = 0; t < 2; ++t) {
      u32 W[4][2];
#pragma unroll
      for (int g = 0; g < 4; ++g)
#pragma unroll
        for (int u = 0; u < 2; ++u)
          W[g][u] = cvtpk_bf16(s[t][4 * g + 2 * u], s[t][4 * g + 2 * u + 1]);
#pragma unroll
      for (int kap = 0; kap < 2; ++kap) {
        u32x2 r0 = __builtin_amdgcn_permlane32_swap(W[2 * kap][0], W[2 * kap + 1][0], false, false);
        u32x2 r1 = __builtin_amdgcn_permlane32_swap(W[2 * kap][1], W[2 * kap + 1][1], false, false);
        u32x4 words = {r0.x, r1.x, r0.y, r1.y};
        bf16x8 pB = __builtin_bit_cast(bf16x8, words);
#pragma unroll
        for (int dt = 0; dt < 2; ++dt)
          o[dt] = __builtin_amdgcn_mfma_f32_32x32x16_bf16(vf[t][kap][dt], pB, o[dt], 0, 0, 0);
      }
    }
  };

  // prologue: stage tile 0 into buf 0
  {
    bf16x8 v0[2];
    issueK(0, 0);
    loadV(0, v0);
    writeV(0, v0);               // compiler inserts the vmcnt wait on v0
  }
  __syncthreads();

  int buf = 0;
  for (int kt = 0; kt < 32; ++kt) {
    // issue next tile's loads BEFORE compute (latency hides under compute)
    bf16x8 nv[2];
    if (kt + 1 < 32) { issueK(buf ^ 1, kt + 1); loadV(kt + 1, nv); }

    // hoist V A-frags for current tile, shared by both branches
    bf16x8 vf[2][2][2];
#pragma unroll
    for (int t = 0; t < 2; ++t)
#pragma unroll
      for (int kap = 0; kap < 2; ++kap)
#pragma unroll
        for (int dt = 0; dt < 2; ++dt) {
          int d = dt * 32 + l31;
          int koff = (t * 32 + kap * 16 + hi * 8) ^ (d & 56);
          vf[t][kap][dt] = *(const bf16x8*)&VTs[buf][d * VLD + koff];
        }

    process(q1f, &K1s[buf][0], vf, m1, ls1, o1);
    process(q2f, &K2s[buf][0], vf, m2, ls2, o2);

    if (kt + 1 < 32) writeV(buf ^ 1, nv);   // write-late (after compute)
    __syncthreads();                        // drains vmcnt (K) + lgkm (V)
    buf ^= 1;
  }

  // ---- epilogue: combine halves, diff, RMSNorm over 64 dims, store bf16 ----
  ls1 += xchg32f(ls1, hi);
  ls2 += xchg32f(ls2, hi);
  const float il1 = 1.0f / ls1, il2 = 1.0f / ls2;

  f32x16 v[2];
  float ssq = 0.f;
#pragma unroll
  for (int dt = 0; dt < 2; ++dt)
#pragma unroll
    for (int i = 0; i < 16; ++i) {
      float a = o1[dt][i] * il1 - lam * (o2[dt][i] * il2);
      v[dt][i] = a;
      ssq += a * a;
    }
  ssq += xchg32f(ssq, hi);
  const float inv = rsqrtf(ssq * (1.0f / 64.0f) + 1e-6f);

  u16* yr = y + (row0 + qrow) * 1024 + head * 64;
#pragma unroll
  for (int dt = 0; dt < 2; ++dt)
#pragma unroll
    for (int rg = 0; rg < 4; ++rg) {
      int dbase = 8 * rg + 4 * hi + 32 * dt;
      u16x4v w;
#pragma unroll
      for (int bb = 0; bb < 4; ++bb)
        w[bb] = f2bf(v[dt][4 * rg + bb] * inv * rms_scale[dbase + bb] * ONE_MINUS_LAMBDA_INIT);
      *(u16x4v*)(yr + dbase) = w;
    }
}

// ---------------------------------------------------------------------------
extern "C" void kernel_launch(void* const* d_in, const int* in_sizes, int n_in,
                              void* d_out, int out_size, void* d_ws, size_t ws_size,
                              hipStream_t stream) {
  const float* x     = (const float*)d_in[0];
  const float* Wqkv  = (const float*)d_in[1];
  const float* Wproj = (const float*)d_in[2];
  const float* lq1   = (const float*)d_in[3];
  const float* lk1   = (const float*)d_in[4];
  const float* lq2   = (const float*)d_in[5];
  const float* lk2   = (const float*)d_in[6];
  const float* rms   = (const float*)d_in[7];
  float* out = (float*)d_out;

  char* ws = (char*)d_ws;
  u16* xb     = (u16*)(ws);                        //  8 MB  [4096][1024]
  u16* WqkvT  = (u16*)(ws + (size_t)(8  << 20));   //  6 MB  [3072][1024]
  u16* WprojT = (u16*)(ws + (size_t)(14 << 20));   //  2 MB  [1024][1024]
  u16* qkvb   = (u16*)(ws + (size_t)(16 << 20));   // 24 MB  [4096][3072]
  u16* yb     = xb;                                //  reuse: xb dead after qkv GEMM

  conv_x_kernel<<<4096, 256, 0, stream>>>(x, xb, 1048576);
  conv_transpose_kernel<<<dim3(48, 16), 256, 0, stream>>>(Wqkv, WqkvT, 1024, 3072);
  conv_transpose_kernel<<<dim3(16, 16), 256, 0, stream>>>(Wproj, WprojT, 1024, 1024);
  gemm_bt<u16><<<dim3(32, 24), 256, 0, stream>>>(xb, WqkvT, qkvb, 4096, 3072, 1024);
  diff_attn_kernel<<<512, 256, 0, stream>>>(qkvb, lq1, lk1, lq2, lk2, rms, yb);
  gemm_bt<float><<<dim3(32, 8), 256, 0, stream>>>(yb, WprojT, out, 4096, 1024, 1024);
}